// Round 6
// baseline (431.273 us; speedup 1.0000x reference)
//
#include <hip/hip_runtime.h>
#include <stdint.h>

// GIN forward: B=32, N=1024, D=128, L=2.
// R9: kA v3 — barrier-free direct-register GEMM.
// Ablation insight: kA has NO intra-block reuse needing LDS (A-frags shared
// across waves -> L1 covers; B-frags disjoint). All staged variants (R5/R8)
// plateaued ~345-350us => barrier-locked staging was the invariant cost
// (m233 regime). New kA: frags global->VGPR direct, 8 loads + 8 MFMA per
// K-chunk, full unroll, no LDS/barriers/asm in main loop; 32-row blocks,
// grid 1024 = 4 blocks/CU. kB/k4/k0 unchanged (isolate delta).

#define BB 32
#define NN 1024
#define DD 128
#define RR 32768  // BB*NN

typedef __bf16 bf16_t;
typedef bf16_t bf16x8 __attribute__((ext_vector_type(8)));
typedef unsigned short us8 __attribute__((ext_vector_type(8)));
typedef float f32x4 __attribute__((ext_vector_type(4)));

__device__ __forceinline__ unsigned short f2b(float f) {
  unsigned u = __float_as_uint(f);
  u += 0x7fff + ((u >> 16) & 1);  // RNE
  return (unsigned short)(u >> 16);
}
__device__ __forceinline__ float b2f(unsigned short s) {
  return __uint_as_float((unsigned)s << 16);
}

#define GLL(GP, LP)                                              \
  __builtin_amdgcn_global_load_lds(                              \
      (const __attribute__((address_space(1))) void*)(GP),       \
      (__attribute__((address_space(3))) void*)(LP), 16, 0, 0)

// ---------------- K0: x->hT (0..255), W->WT (256..511), adj->bf16 (512..) ---
__global__ __launch_bounds__(256) void k0_prep(const float* __restrict__ x,
                                               const float* __restrict__ adj,
                                               const float* __restrict__ W1,
                                               const float* __restrict__ W2,
                                               unsigned short* __restrict__ hT,
                                               unsigned short* __restrict__ W1T,
                                               unsigned short* __restrict__ W2T,
                                               unsigned short* __restrict__ adjB) {
  const int tid = threadIdx.x;
  if (blockIdx.x >= 512) {
    size_t i8 = ((size_t)(blockIdx.x - 512) * 256 + tid) * 8;
    float4 a = *(const float4*)(adj + i8);
    float4 b = *(const float4*)(adj + i8 + 4);
    alignas(16) unsigned short t[8] = {f2b(a.x), f2b(a.y), f2b(a.z), f2b(a.w),
                                       f2b(b.x), f2b(b.y), f2b(b.z), f2b(b.w)};
    *(uint4*)(adjB + i8) = *(const uint4*)t;
    return;
  }
  if (blockIdx.x < 256) {
    const int b = blockIdx.x >> 3, nt = blockIdx.x & 7;
    __shared__ alignas(16) unsigned short T[128][136];
    const int r = tid >> 1, c0 = (tid & 1) * 64;
    const float* src = x + ((size_t)(b * 8 + nt) * 128 + r) * 128 + c0;
#pragma unroll
    for (int i = 0; i < 64; i += 4) {
      float4 v = *(const float4*)(src + i);
      int c = c0 + i;
      T[c][r] = f2b(v.x); T[c + 1][r] = f2b(v.y);
      T[c + 2][r] = f2b(v.z); T[c + 3][r] = f2b(v.w);
    }
    __syncthreads();
    const int d = tid >> 1, n0 = (tid & 1) * 64;
    unsigned short* dst = hT + ((size_t)b * DD + d) * NN + nt * 128 + n0;
#pragma unroll
    for (int i = 0; i < 64; i += 8)
      *(uint4*)(dst + i) = *(const uint4*)&T[d][n0 + i];
  } else {
    int idx = (blockIdx.x - 256) * 256 + tid;  // 0..65535
    int w = idx >> 15;
    int rem = idx & 32767;
    int l = rem >> 14;
    int n = (rem >> 7) & 127;
    int k = rem & 127;
    const float* W = w ? W2 : W1;
    unsigned short* WT = w ? W2T : W1T;
    WT[((size_t)l * 128 + n) * 128 + k] = f2b(W[((size_t)l * 128 + k) * 128 + n]);
  }
}

// ---------------- kA v3: pooled (adjB@hT) + z1 = pooled@W1 + b1 + stats -----
// 32 adj-rows x 128 d per block; 4 waves, wave w owns cols 32w..32w+31.
// Direct global->VGPR fragment loads, no LDS/barriers in the K-loop.
__global__ __launch_bounds__(256, 4) void kA_pool_lin(
    const unsigned short* __restrict__ adjB, const unsigned short* __restrict__ hT,
    const unsigned short* __restrict__ WT, const float* __restrict__ bias,
    unsigned short* __restrict__ z1b, float* __restrict__ gsum,
    float* __restrict__ gsq) {
  const int mt = blockIdx.x, b = blockIdx.y;
  const int tid = threadIdx.x;
  const int wave = tid >> 6, lane = tid & 63;
  const int wc = wave * 32;
  const int ln = lane & 15, q = lane >> 4;

  __shared__ alignas(16) unsigned short As2[32][136];  // pooled exchange, 8.7KB

  // per-lane fragment base pointers
  const unsigned short* pA = adjB + ((size_t)b * NN + mt * 32 + ln) * NN + q * 8;
  const unsigned short* pB = hT + ((size_t)b * DD + wc + ln) * NN + q * 8;

  f32x4 acc1[2][2];
  f32x4 zero = {0.f, 0.f, 0.f, 0.f};
#pragma unroll
  for (int i = 0; i < 2; i++) { acc1[i][0] = zero; acc1[i][1] = zero; }

  // [buf][i or j][kk] fragment double-buffer (64 VGPR)
  bf16x8 fa[2][2][2], fb[2][2][2];

#define LOADC(BUF, K0)                                                        \
  do {                                                                        \
    _Pragma("unroll") for (int ii = 0; ii < 2; ii++)                          \
        _Pragma("unroll") for (int kk = 0; kk < 2; kk++)                      \
            fa[BUF][ii][kk] =                                                 \
                *(const bf16x8*)(pA + (size_t)(ii * 16) * NN + (K0) + kk * 32);\
    _Pragma("unroll") for (int jj = 0; jj < 2; jj++)                          \
        _Pragma("unroll") for (int kk = 0; kk < 2; kk++)                      \
            fb[BUF][jj][kk] =                                                 \
                *(const bf16x8*)(pB + (size_t)(jj * 16) * NN + (K0) + kk * 32);\
  } while (0)

  LOADC(0, 0);
  LOADC(1, 64);

#pragma unroll
  for (int t = 0; t < 16; ++t) {
    const int cur = t & 1;  // constant after unroll
#pragma unroll
    for (int kk = 0; kk < 2; kk++)
#pragma unroll
      for (int i = 0; i < 2; i++)
#pragma unroll
        for (int j = 0; j < 2; j++)
          acc1[i][j] = __builtin_amdgcn_mfma_f32_16x16x32_bf16(
              fa[cur][i][kk], fb[cur][j][kk], acc1[i][j], 0, 0, 0);
    if (t + 2 < 16) LOADC(cur, (t + 2) * 64);
  }
#undef LOADC

  // pooled tile -> LDS (bf16), A-layout for phase 2
#pragma unroll
  for (int i = 0; i < 2; i++) {
    int row = i * 16 + q * 4;
#pragma unroll
    for (int j = 0; j < 2; j++) {
      int col = wc + j * 16 + ln;
#pragma unroll
      for (int r = 0; r < 4; r++) As2[row + r][col] = f2b(acc1[i][j][r]);
    }
  }
  __syncthreads();

  // phase 2: z1 = pooled @ W1 (K=128; W frags read from L2, short live range)
  f32x4 acc2[2][2];
#pragma unroll
  for (int i = 0; i < 2; i++) { acc2[i][0] = zero; acc2[i][1] = zero; }
#pragma unroll
  for (int ks = 0; ks < 4; ks++) {
    bf16x8 af[2], wf[2];
#pragma unroll
    for (int i = 0; i < 2; i++)
      af[i] = *(const bf16x8*)&As2[i * 16 + ln][ks * 32 + q * 8];
#pragma unroll
    for (int j = 0; j < 2; j++)
      wf[j] = *(const bf16x8*)&WT[(size_t)(wc + j * 16 + ln) * 128 + ks * 32 + q * 8];
#pragma unroll
    for (int i = 0; i < 2; i++)
#pragma unroll
      for (int j = 0; j < 2; j++)
        acc2[i][j] = __builtin_amdgcn_mfma_f32_16x16x32_bf16(af[i], wf[j], acc2[i][j], 0, 0, 0);
  }

  // epilogue: +bias, write z1 bf16, column stats (cols unique per wave)
  const size_t row0 = (size_t)b * NN + mt * 32;
#pragma unroll
  for (int j = 0; j < 2; j++) {
    int col = wc + j * 16 + ln;
    float bc = bias[col];
    float s1 = 0.f, s2 = 0.f;
#pragma unroll
    for (int i = 0; i < 2; i++) {
      int row = i * 16 + q * 4;
#pragma unroll
      for (int r = 0; r < 4; r++) {
        float v = acc2[i][j][r] + bc;
        z1b[(row0 + row + r) * 128 + col] = f2b(v);
        s1 += v; s2 += v * v;
      }
    }
    s1 += __shfl_xor(s1, 16); s1 += __shfl_xor(s1, 32);
    s2 += __shfl_xor(s2, 16); s2 += __shfl_xor(s2, 32);
    if (q == 0) { atomicAdd(&gsum[col], s1); atomicAdd(&gsq[col], s2); }
  }
}

// ---------------- kB: z2 = relu(BN(z1)) @ W2 + b2 + stats ----------------
// W frags in regs; raw z1 via GLL (swizzled src); BN fused into frag read.
__global__ __launch_bounds__(256, 2) void kB_lin(
    const unsigned short* __restrict__ Zin, const float* __restrict__ gsum_in,
    const float* __restrict__ gsq_in, const float* __restrict__ gamma,
    const float* __restrict__ beta, const unsigned short* __restrict__ WT,
    const float* __restrict__ bias, unsigned short* __restrict__ z2b,
    float* __restrict__ gsum, float* __restrict__ gsq) {
  const int mt = blockIdx.x;
  const int tid = threadIdx.x;
  const int wave = tid >> 6, lane = tid & 63;
  const int wc = wave * 32;
  const int ln = lane & 15, q = lane >> 4;

  __shared__ alignas(16) unsigned short Az[64 * 128];  // raw z1, 16 KB
  __shared__ float nsc[128], nsh[128];

  // W2 fragments -> registers
  bf16x8 wfr[4][2];
#pragma unroll
  for (int ks = 0; ks < 4; ks++)
#pragma unroll
    for (int j = 0; j < 2; j++)
      wfr[ks][j] = *(const bf16x8*)&WT[(size_t)(wc + j * 16 + ln) * 128 + ks * 32 + q * 8];

  // stage raw z1 tile 64x128 via GLL, source-swizzled (rows 256B = 16 units)
  const size_t row0 = (size_t)mt * 64;
  const int rZ = tid >> 4;                            // 0..15
  const int uZ = (((tid & 15) ^ (rZ & 7)) << 3);      // shorts
  const unsigned short* gZ = Zin + (row0 + rZ) * 128 + uZ;
  GLL(gZ, Az + tid * 8);
  GLL(gZ + 16 * 128, Az + 2048 + tid * 8);
  GLL(gZ + 32 * 128, Az + 4096 + tid * 8);
  GLL(gZ + 48 * 128, Az + 6144 + tid * 8);

  if (tid < 128) {
    float mean = gsum_in[tid] * (1.f / 32768.f);
    float var = gsq_in[tid] * (1.f / 32768.f) - mean * mean;
    float sc = gamma[tid] * rsqrtf(var + 1e-5f);
    nsc[tid] = sc; nsh[tid] = beta[tid] - mean * sc;
  }
  __syncthreads();  // GLL landed (vmcnt0 implied) + nsc/nsh ready

  f32x4 acc[4][2];
  f32x4 zero = {0.f, 0.f, 0.f, 0.f};
#pragma unroll
  for (int i = 0; i < 4; i++) { acc[i][0] = zero; acc[i][1] = zero; }

  const int xorv = (ln & 7) << 4;
#pragma unroll
  for (int ks = 0; ks < 4; ks++) {
    bf16x8 af[4];
#pragma unroll
    for (int i = 0; i < 4; i++) {
      us8 raw = *(const us8*)((const char*)Az + (i * 16 + ln) * 256 +
                              (((ks << 6) + (q << 4)) ^ xorv));
      us8 t;
#pragma unroll
      for (int e = 0; e < 8; e++) {
        int col = ks * 32 + q * 8 + e;
        t[e] = f2b(fmaxf(fmaf(b2f(raw[e]), nsc[col], nsh[col]), 0.f));
      }
      af[i] = *(bf16x8*)&t;
    }
#pragma unroll
    for (int i = 0; i < 4; i++)
#pragma unroll
      for (int j = 0; j < 2; j++)
        acc[i][j] = __builtin_amdgcn_mfma_f32_16x16x32_bf16(af[i], wfr[ks][j], acc[i][j], 0, 0, 0);
  }

#pragma unroll
  for (int j = 0; j < 2; j++) {
    int col = wc + j * 16 + ln;
    float bc = bias[col];
    float s1 = 0.f, s2 = 0.f;
#pragma unroll
    for (int i = 0; i < 4; i++) {
      int row = i * 16 + q * 4;
#pragma unroll
      for (int r = 0; r < 4; r++) {
        float v = acc[i][j][r] + bc;
        z2b[(row0 + row + r) * 128 + col] = f2b(v);
        s1 += v; s2 += v * v;
      }
    }
    s1 += __shfl_xor(s1, 16); s1 += __shfl_xor(s1, 32);
    s2 += __shfl_xor(s2, 16); s2 += __shfl_xor(s2, 32);
    if (q == 0) { atomicAdd(&gsum[col], s1); atomicAdd(&gsq[col], s2); }
  }
}

// -------- K4t: h = relu(BN(z2)) -> hT bf16 [b][d][n] (LDS transpose) --------
__global__ __launch_bounds__(256) void k4_bnt(const unsigned short* __restrict__ Z,
                                              const float* __restrict__ gsum,
                                              const float* __restrict__ gsq,
                                              const float* __restrict__ gamma,
                                              const float* __restrict__ beta,
                                              unsigned short* __restrict__ hT) {
  const int b = blockIdx.x, nt = blockIdx.y, tid = threadIdx.x;
  __shared__ alignas(16) unsigned short T[128][136];
  __shared__ float nsc[128], nsh[128];
  if (tid < 128) {
    float mean = gsum[tid] * (1.f / 32768.f);
    float var = gsq[tid] * (1.f / 32768.f) - mean * mean;
    float sc = gamma[tid] * rsqrtf(var + 1e-5f);
    nsc[tid] = sc; nsh[tid] = beta[tid] - mean * sc;
  }
  __syncthreads();
  const int r = tid >> 1, c0 = (tid & 1) * 64;
  const unsigned short* src = Z + ((size_t)(b * 8 + nt) * 128 + r) * 128 + c0;
#pragma unroll
  for (int u = 0; u < 8; u++) {
    uint4 raw = *(const uint4*)(src + u * 8);
    const unsigned short* s = (const unsigned short*)&raw;
#pragma unroll
    for (int e = 0; e < 8; e++) {
      int c = c0 + u * 8 + e;
      T[c][r] = f2b(fmaxf(fmaf(b2f(s[e]), nsc[c], nsh[c]), 0.f));
    }
  }
  __syncthreads();
  const int d = tid >> 1, n0 = (tid & 1) * 64;
  unsigned short* dst = hT + ((size_t)b * DD + d) * NN + nt * 128 + n0;
#pragma unroll
  for (int i = 0; i < 64; i += 8)
    *(uint4*)(dst + i) = *(const uint4*)&T[d][n0 + i];
}

// -------- K4e: final h = relu(BN(z2)) -> d_out f32 [b][n][d] --------
__global__ __launch_bounds__(256) void k4_out(const unsigned short* __restrict__ Z,
                                              const float* __restrict__ gsum,
                                              const float* __restrict__ gsq,
                                              const float* __restrict__ gamma,
                                              const float* __restrict__ beta,
                                              float* __restrict__ out) {
  const int blk = blockIdx.x, tid = threadIdx.x;
  __shared__ float nsc[128], nsh[128];
  if (tid < 128) {
    float mean = gsum[tid] * (1.f / 32768.f);
    float var = gsq[tid] * (1.f / 32768.f) - mean * mean;
    float sc = gamma[tid] * rsqrtf(var + 1e-5f);
    nsc[tid] = sc; nsh[tid] = beta[tid] - mean * sc;
  }
  __syncthreads();
  const int r = tid >> 1, c0 = (tid & 1) * 64;
  const unsigned short* src = Z + ((size_t)blk * 128 + r) * 128 + c0;
  float* dst = out + ((size_t)blk * 128 + r) * 128 + c0;
#pragma unroll
  for (int u = 0; u < 8; u++) {
    uint4 raw = *(const uint4*)(src + u * 8);
    const unsigned short* s = (const unsigned short*)&raw;
    float4 o;
    int c = c0 + u * 8;
    o.x = fmaxf(fmaf(b2f(s[0]), nsc[c], nsh[c]), 0.f);
    o.y = fmaxf(fmaf(b2f(s[1]), nsc[c + 1], nsh[c + 1]), 0.f);
    o.z = fmaxf(fmaf(b2f(s[2]), nsc[c + 2], nsh[c + 2]), 0.f);
    o.w = fmaxf(fmaf(b2f(s[3]), nsc[c + 3], nsh[c + 3]), 0.f);
    *(float4*)(dst + u * 8) = o;
    o.x = fmaxf(fmaf(b2f(s[4]), nsc[c + 4], nsh[c + 4]), 0.f);
    o.y = fmaxf(fmaf(b2f(s[5]), nsc[c + 5], nsh[c + 5]), 0.f);
    o.z = fmaxf(fmaf(b2f(s[6]), nsc[c + 6], nsh[c + 6]), 0.f);
    o.w = fmaxf(fmaf(b2f(s[7]), nsc[c + 7], nsh[c + 7]), 0.f);
    *(float4*)(dst + u * 8 + 4) = o;
  }
}

extern "C" void kernel_launch(void* const* d_in, const int* in_sizes, int n_in,
                              void* d_out, int out_size, void* d_ws, size_t ws_size,
                              hipStream_t stream) {
  const float* x = (const float*)d_in[0];
  const float* adj = (const float*)d_in[2];
  const float* W1 = (const float*)d_in[3];
  const float* b1 = (const float*)d_in[4];
  const float* W2 = (const float*)d_in[5];
  const float* b2 = (const float*)d_in[6];
  const float* g_in = (const float*)d_in[7];
  const float* be_in = (const float*)d_in[8];
  const float* g_out = (const float*)d_in[9];
  const float* be_out = (const float*)d_in[10];
  float* out = (float*)d_out;

  char* ws = (char*)d_ws;
  unsigned short* hT = (unsigned short*)ws;                           // 8 MB
  unsigned short* z1b = (unsigned short*)(ws + 8ull * 1024 * 1024);   // 8 MB
  unsigned short* z2b = (unsigned short*)(ws + 16ull * 1024 * 1024);  // 8 MB
  unsigned short* W1T = (unsigned short*)(ws + 24ull * 1024 * 1024);  // 64 KB
  unsigned short* W2T = W1T + 2 * 128 * 128;                          // 64 KB
  float* stats = (float*)(ws + 25ull * 1024 * 1024);                  // 4 x 256 f32
  unsigned short* adjB = (unsigned short*)(ws + 26ull * 1024 * 1024); // 64 MB

  hipMemsetAsync(stats, 0, 4 * 256 * sizeof(float), stream);
  k0_prep<<<512 + 16384, 256, 0, stream>>>(x, adj, W1, W2, hT, W1T, W2T, adjB);

  for (int l = 0; l < 2; l++) {
    float* st_in = stats + (l * 2 + 0) * 256;
    float* st_out = stats + (l * 2 + 1) * 256;
    kA_pool_lin<<<dim3(32, 32), 256, 0, stream>>>(adjB, hT, W1T + l * 16384,
                                                  b1 + l * 128, z1b, st_in,
                                                  st_in + 128);
    kB_lin<<<512, 256, 0, stream>>>(z1b, st_in, st_in + 128, g_in + l * 128,
                                    be_in + l * 128, W2T + l * 16384,
                                    b2 + l * 128, z2b, st_out, st_out + 128);
    if (l == 0)
      k4_bnt<<<dim3(32, 8), 256, 0, stream>>>(z2b, st_out, st_out + 128, g_out,
                                              be_out, hT);
    else
      k4_out<<<256, 256, 0, stream>>>(z2b, st_out, st_out + 128, g_out + 128,
                                      be_out + 128, out);
  }
}

// Round 7
// 333.220 us; speedup vs baseline: 1.2943x; 1.2943x over previous
//
#include <hip/hip_runtime.h>
#include <stdint.h>

// GIN forward: B=32, N=1024, D=128, L=2.
// R10: kA BM=128 big-tile (halve B staging amplification 192->128MB),
// XCD-local batch swizzle (B-tile pulled into ONE L2), depth-3 GLL,
// 96KB LDS, grid 256 = 1 block/CU. stats-memset folded into k0.
// kB/k4t/k4e identical to R8 (isolate kA delta). R9's direct-reg kA
// reverted (uncoalesced 16B/lane scatter, +80us).

#define BB 32
#define NN 1024
#define DD 128
#define RR 32768  // BB*NN

typedef __bf16 bf16_t;
typedef bf16_t bf16x8 __attribute__((ext_vector_type(8)));
typedef unsigned short us8 __attribute__((ext_vector_type(8)));
typedef float f32x4 __attribute__((ext_vector_type(4)));

__device__ __forceinline__ unsigned short f2b(float f) {
  unsigned u = __float_as_uint(f);
  u += 0x7fff + ((u >> 16) & 1);  // RNE
  return (unsigned short)(u >> 16);
}
__device__ __forceinline__ float b2f(unsigned short s) {
  return __uint_as_float((unsigned)s << 16);
}

#define GLL(GP, LP)                                              \
  __builtin_amdgcn_global_load_lds(                              \
      (const __attribute__((address_space(1))) void*)(GP),       \
      (__attribute__((address_space(3))) void*)(LP), 16, 0, 0)

// ---------------- K0: x->hT (0..255), W->WT + stats zero (256..511),
// ----------------     adj f32->bf16 (512..) ---------------------------------
__global__ __launch_bounds__(256) void k0_prep(const float* __restrict__ x,
                                               const float* __restrict__ adj,
                                               const float* __restrict__ W1,
                                               const float* __restrict__ W2,
                                               unsigned short* __restrict__ hT,
                                               unsigned short* __restrict__ W1T,
                                               unsigned short* __restrict__ W2T,
                                               unsigned short* __restrict__ adjB,
                                               float* __restrict__ stats) {
  const int tid = threadIdx.x;
  if (blockIdx.x >= 512) {
    size_t i8 = ((size_t)(blockIdx.x - 512) * 256 + tid) * 8;
    float4 a = *(const float4*)(adj + i8);
    float4 b = *(const float4*)(adj + i8 + 4);
    alignas(16) unsigned short t[8] = {f2b(a.x), f2b(a.y), f2b(a.z), f2b(a.w),
                                       f2b(b.x), f2b(b.y), f2b(b.z), f2b(b.w)};
    *(uint4*)(adjB + i8) = *(const uint4*)t;
    return;
  }
  if (blockIdx.x < 256) {
    const int b = blockIdx.x >> 3, nt = blockIdx.x & 7;
    __shared__ alignas(16) unsigned short T[128][136];
    const int r = tid >> 1, c0 = (tid & 1) * 64;
    const float* src = x + ((size_t)(b * 8 + nt) * 128 + r) * 128 + c0;
#pragma unroll
    for (int i = 0; i < 64; i += 4) {
      float4 v = *(const float4*)(src + i);
      int c = c0 + i;
      T[c][r] = f2b(v.x); T[c + 1][r] = f2b(v.y);
      T[c + 2][r] = f2b(v.z); T[c + 3][r] = f2b(v.w);
    }
    __syncthreads();
    const int d = tid >> 1, n0 = (tid & 1) * 64;
    unsigned short* dst = hT + ((size_t)b * DD + d) * NN + nt * 128 + n0;
#pragma unroll
    for (int i = 0; i < 64; i += 8)
      *(uint4*)(dst + i) = *(const uint4*)&T[d][n0 + i];
  } else {
    if (blockIdx.x == 256) {  // zero BN-stat accumulators (4 x 256 f32)
      stats[tid] = 0.f; stats[256 + tid] = 0.f;
      stats[512 + tid] = 0.f; stats[768 + tid] = 0.f;
    }
    int idx = (blockIdx.x - 256) * 256 + tid;  // 0..65535
    int w = idx >> 15;
    int rem = idx & 32767;
    int l = rem >> 14;
    int n = (rem >> 7) & 127;
    int k = rem & 127;
    const float* W = w ? W2 : W1;
    unsigned short* WT = w ? W2T : W1T;
    WT[((size_t)l * 128 + n) * 128 + k] = f2b(W[((size_t)l * 128 + k) * 128 + n]);
  }
}

// ---------------- kA: pooled (adjB@hT) fused with z1 = pooled@W1 + b1 + stats
// BM=128: 128 adj-rows x 128 d per block; grid 256 (1/CU); depth-3 GLL,
// vmcnt(16); XCD-local batch mapping b = (blk&7) | ((blk>>6)<<3).
__global__ __launch_bounds__(256, 1) void kA_pool_lin(
    const unsigned short* __restrict__ adjB, const unsigned short* __restrict__ hT,
    const unsigned short* __restrict__ WT, const float* __restrict__ bias,
    unsigned short* __restrict__ z1b, float* __restrict__ gsum,
    float* __restrict__ gsq) {
  const int blk = blockIdx.x;
  const int b = (blk & 7) | ((blk >> 6) << 3);  // same b -> same XCD
  const int mt = (blk >> 3) & 7;
  const int tid = threadIdx.x;
  const int wave = tid >> 6, lane = tid & 63;
  const int wc = wave * 32;
  const int ln = lane & 15, q = lane >> 4;

  __shared__ union {
    struct {
      unsigned short A[3][8192];  // [buf][128 x 64 bf16] 16 KB each
      unsigned short B[3][8192];  // [buf][128 x 64 bf16] 16 KB each
    } s;
    unsigned short As2[128][136];  // pooled exchange tile (34.8 KB)
  } sm;

  const unsigned short* adjb = adjB + ((size_t)b * NN + mt * 128) * NN;
  const unsigned short* hTb = hT + (size_t)b * DD * NN;

  // per-thread staging source (XOR source-swizzle within 8x16B row)
  const int srow = tid >> 3;                         // 0..31
  const int sseg = (((tid & 7) ^ (srow & 7)) << 3);  // shorts
  const unsigned short* gA = adjb + (size_t)srow * NN + sseg;  // rows +0/32/64/96
  const unsigned short* gB = hTb + (size_t)srow * NN + sseg;   // rows +0/32/64/96

#define STAGE(P, K0)                                \
  do {                                              \
    unsigned short* ap = sm.s.A[(P)];               \
    unsigned short* bp = sm.s.B[(P)];               \
    GLL(gA + (K0), ap + tid * 8);                   \
    GLL(gA + 32 * NN + (K0), ap + 2048 + tid * 8);  \
    GLL(gA + 64 * NN + (K0), ap + 4096 + tid * 8);  \
    GLL(gA + 96 * NN + (K0), ap + 6144 + tid * 8);  \
    GLL(gB + (K0), bp + tid * 8);                   \
    GLL(gB + 32 * NN + (K0), bp + 2048 + tid * 8);  \
    GLL(gB + 64 * NN + (K0), bp + 4096 + tid * 8);  \
    GLL(gB + 96 * NN + (K0), bp + 6144 + tid * 8);  \
  } while (0)

  STAGE(0, 0);
  STAGE(1, 64);
  STAGE(2, 128);

  f32x4 acc1[8][2];
  f32x4 zero = {0.f, 0.f, 0.f, 0.f};
#pragma unroll
  for (int i = 0; i < 8; i++) { acc1[i][0] = zero; acc1[i][1] = zero; }

  const int xorv = (ln & 7) << 4;  // byte XOR on read side (same involution)

#pragma unroll
  for (int t = 0; t < 16; ++t) {
    const int p = t % 3;
    if (t < 14)
      asm volatile("s_waitcnt vmcnt(16)" ::: "memory");  // t landed; t+1,t+2 in flight
    else if (t == 14)
      asm volatile("s_waitcnt vmcnt(8)" ::: "memory");
    else
      asm volatile("s_waitcnt vmcnt(0)" ::: "memory");
    __builtin_amdgcn_s_barrier();
    __builtin_amdgcn_sched_barrier(0);
    {
      const char* Ab = (const char*)sm.s.A[p];
      const char* Bb = (const char*)sm.s.B[p];
#pragma unroll
      for (int kk = 0; kk < 2; kk++) {
        const int co = ((kk << 6) + (q << 4)) ^ xorv;
        bf16x8 af[8], bfr[2];
#pragma unroll
        for (int i = 0; i < 8; i++)
          af[i] = *(const bf16x8*)(Ab + (i * 16 + ln) * 128 + co);
#pragma unroll
        for (int j = 0; j < 2; j++)
          bfr[j] = *(const bf16x8*)(Bb + (wc + j * 16 + ln) * 128 + co);
#pragma unroll
        for (int i = 0; i < 8; i++)
#pragma unroll
          for (int j = 0; j < 2; j++)
            acc1[i][j] = __builtin_amdgcn_mfma_f32_16x16x32_bf16(af[i], bfr[j], acc1[i][j], 0, 0, 0);
      }
    }
    __builtin_amdgcn_sched_barrier(0);
    __builtin_amdgcn_s_barrier();  // all waves done reading buf p
    __builtin_amdgcn_sched_barrier(0);
    if (t < 13) STAGE(p, (t + 3) * 64);
  }
#undef STAGE

  // pooled tile -> LDS (bf16), A-layout for phase 2 (overwrites stage area)
#pragma unroll
  for (int i = 0; i < 8; i++) {
    int row = i * 16 + q * 4;
#pragma unroll
    for (int j = 0; j < 2; j++) {
      int col = wc + j * 16 + ln;
#pragma unroll
      for (int r = 0; r < 4; r++) sm.As2[row + r][col] = f2b(acc1[i][j][r]);
    }
  }
  __syncthreads();

  // phase 2: z1 = pooled @ W1 (K=128; W frags from L2, short live range)
  f32x4 acc2[8][2];
#pragma unroll
  for (int i = 0; i < 8; i++) { acc2[i][0] = zero; acc2[i][1] = zero; }
#pragma unroll
  for (int ks = 0; ks < 4; ks++) {
    bf16x8 af[8], wf[2];
#pragma unroll
    for (int i = 0; i < 8; i++)
      af[i] = *(const bf16x8*)&sm.As2[i * 16 + ln][ks * 32 + q * 8];
#pragma unroll
    for (int j = 0; j < 2; j++)
      wf[j] = *(const bf16x8*)&WT[(size_t)(wc + j * 16 + ln) * 128 + ks * 32 + q * 8];
#pragma unroll
    for (int i = 0; i < 8; i++)
#pragma unroll
      for (int j = 0; j < 2; j++)
        acc2[i][j] = __builtin_amdgcn_mfma_f32_16x16x32_bf16(af[i], wf[j], acc2[i][j], 0, 0, 0);
  }

  // epilogue: +bias, write z1 bf16, column stats (cols unique per wave)
  const size_t row0 = (size_t)b * NN + mt * 128;
#pragma unroll
  for (int j = 0; j < 2; j++) {
    int col = wc + j * 16 + ln;
    float bc = bias[col];
    float s1 = 0.f, s2 = 0.f;
#pragma unroll
    for (int i = 0; i < 8; i++) {
      int row = i * 16 + q * 4;
#pragma unroll
      for (int r = 0; r < 4; r++) {
        float v = acc2[i][j][r] + bc;
        z1b[(row0 + row + r) * 128 + col] = f2b(v);
        s1 += v; s2 += v * v;
      }
    }
    s1 += __shfl_xor(s1, 16); s1 += __shfl_xor(s1, 32);
    s2 += __shfl_xor(s2, 16); s2 += __shfl_xor(s2, 32);
    if (q == 0) { atomicAdd(&gsum[col], s1); atomicAdd(&gsq[col], s2); }
  }
}

// ---------------- kB: z2 = relu(BN(z1)) @ W2 + b2 + stats ----------------
// W frags in regs; raw z1 via GLL (swizzled src); BN fused into frag read.
__global__ __launch_bounds__(256, 2) void kB_lin(
    const unsigned short* __restrict__ Zin, const float* __restrict__ gsum_in,
    const float* __restrict__ gsq_in, const float* __restrict__ gamma,
    const float* __restrict__ beta, const unsigned short* __restrict__ WT,
    const float* __restrict__ bias, unsigned short* __restrict__ z2b,
    float* __restrict__ gsum, float* __restrict__ gsq) {
  const int mt = blockIdx.x;
  const int tid = threadIdx.x;
  const int wave = tid >> 6, lane = tid & 63;
  const int wc = wave * 32;
  const int ln = lane & 15, q = lane >> 4;

  __shared__ alignas(16) unsigned short Az[64 * 128];  // raw z1, 16 KB
  __shared__ float nsc[128], nsh[128];

  // W2 fragments -> registers
  bf16x8 wfr[4][2];
#pragma unroll
  for (int ks = 0; ks < 4; ks++)
#pragma unroll
    for (int j = 0; j < 2; j++)
      wfr[ks][j] = *(const bf16x8*)&WT[(size_t)(wc + j * 16 + ln) * 128 + ks * 32 + q * 8];

  // stage raw z1 tile 64x128 via GLL, source-swizzled (rows 256B = 16 units)
  const size_t row0 = (size_t)mt * 64;
  const int rZ = tid >> 4;                            // 0..15
  const int uZ = (((tid & 15) ^ (rZ & 7)) << 3);      // shorts
  const unsigned short* gZ = Zin + (row0 + rZ) * 128 + uZ;
  GLL(gZ, Az + tid * 8);
  GLL(gZ + 16 * 128, Az + 2048 + tid * 8);
  GLL(gZ + 32 * 128, Az + 4096 + tid * 8);
  GLL(gZ + 48 * 128, Az + 6144 + tid * 8);

  if (tid < 128) {
    float mean = gsum_in[tid] * (1.f / 32768.f);
    float var = gsq_in[tid] * (1.f / 32768.f) - mean * mean;
    float sc = gamma[tid] * rsqrtf(var + 1e-5f);
    nsc[tid] = sc; nsh[tid] = beta[tid] - mean * sc;
  }
  __syncthreads();  // GLL landed (vmcnt0 implied) + nsc/nsh ready

  f32x4 acc[4][2];
  f32x4 zero = {0.f, 0.f, 0.f, 0.f};
#pragma unroll
  for (int i = 0; i < 4; i++) { acc[i][0] = zero; acc[i][1] = zero; }

  const int xorv = (ln & 7) << 4;
#pragma unroll
  for (int ks = 0; ks < 4; ks++) {
    bf16x8 af[4];
#pragma unroll
    for (int i = 0; i < 4; i++) {
      us8 raw = *(const us8*)((const char*)Az + (i * 16 + ln) * 256 +
                              (((ks << 6) + (q << 4)) ^ xorv));
      us8 t;
#pragma unroll
      for (int e = 0; e < 8; e++) {
        int col = ks * 32 + q * 8 + e;
        t[e] = f2b(fmaxf(fmaf(b2f(raw[e]), nsc[col], nsh[col]), 0.f));
      }
      af[i] = *(bf16x8*)&t;
    }
#pragma unroll
    for (int i = 0; i < 4; i++)
#pragma unroll
      for (int j = 0; j < 2; j++)
        acc[i][j] = __builtin_amdgcn_mfma_f32_16x16x32_bf16(af[i], wfr[ks][j], acc[i][j], 0, 0, 0);
  }

#pragma unroll
  for (int j = 0; j < 2; j++) {
    int col = wc + j * 16 + ln;
    float bc = bias[col];
    float s1 = 0.f, s2 = 0.f;
#pragma unroll
    for (int i = 0; i < 4; i++) {
      int row = i * 16 + q * 4;
#pragma unroll
      for (int r = 0; r < 4; r++) {
        float v = acc[i][j][r] + bc;
        z2b[(row0 + row + r) * 128 + col] = f2b(v);
        s1 += v; s2 += v * v;
      }
    }
    s1 += __shfl_xor(s1, 16); s1 += __shfl_xor(s1, 32);
    s2 += __shfl_xor(s2, 16); s2 += __shfl_xor(s2, 32);
    if (q == 0) { atomicAdd(&gsum[col], s1); atomicAdd(&gsq[col], s2); }
  }
}

// -------- K4t: h = relu(BN(z2)) -> hT bf16 [b][d][n] (LDS transpose) --------
__global__ __launch_bounds__(256) void k4_bnt(const unsigned short* __restrict__ Z,
                                              const float* __restrict__ gsum,
                                              const float* __restrict__ gsq,
                                              const float* __restrict__ gamma,
                                              const float* __restrict__ beta,
                                              unsigned short* __restrict__ hT) {
  const int b = blockIdx.x, nt = blockIdx.y, tid = threadIdx.x;
  __shared__ alignas(16) unsigned short T[128][136];
  __shared__ float nsc[128], nsh[128];
  if (tid < 128) {
    float mean = gsum[tid] * (1.f / 32768.f);
    float var = gsq[tid] * (1.f / 32768.f) - mean * mean;
    float sc = gamma[tid] * rsqrtf(var + 1e-5f);
    nsc[tid] = sc; nsh[tid] = beta[tid] - mean * sc;
  }
  __syncthreads();
  const int r = tid >> 1, c0 = (tid & 1) * 64;
  const unsigned short* src = Z + ((size_t)(b * 8 + nt) * 128 + r) * 128 + c0;
#pragma unroll
  for (int u = 0; u < 8; u++) {
    uint4 raw = *(const uint4*)(src + u * 8);
    const unsigned short* s = (const unsigned short*)&raw;
#pragma unroll
    for (int e = 0; e < 8; e++) {
      int c = c0 + u * 8 + e;
      T[c][r] = f2b(fmaxf(fmaf(b2f(s[e]), nsc[c], nsh[c]), 0.f));
    }
  }
  __syncthreads();
  const int d = tid >> 1, n0 = (tid & 1) * 64;
  unsigned short* dst = hT + ((size_t)b * DD + d) * NN + nt * 128 + n0;
#pragma unroll
  for (int i = 0; i < 64; i += 8)
    *(uint4*)(dst + i) = *(const uint4*)&T[d][n0 + i];
}

// -------- K4e: final h = relu(BN(z2)) -> d_out f32 [b][n][d] --------
__global__ __launch_bounds__(256) void k4_out(const unsigned short* __restrict__ Z,
                                              const float* __restrict__ gsum,
                                              const float* __restrict__ gsq,
                                              const float* __restrict__ gamma,
                                              const float* __restrict__ beta,
                                              float* __restrict__ out) {
  const int blk = blockIdx.x, tid = threadIdx.x;
  __shared__ float nsc[128], nsh[128];
  if (tid < 128) {
    float mean = gsum[tid] * (1.f / 32768.f);
    float var = gsq[tid] * (1.f / 32768.f) - mean * mean;
    float sc = gamma[tid] * rsqrtf(var + 1e-5f);
    nsc[tid] = sc; nsh[tid] = beta[tid] - mean * sc;
  }
  __syncthreads();
  const int r = tid >> 1, c0 = (tid & 1) * 64;
  const unsigned short* src = Z + ((size_t)blk * 128 + r) * 128 + c0;
  float* dst = out + ((size_t)blk * 128 + r) * 128 + c0;
#pragma unroll
  for (int u = 0; u < 8; u++) {
    uint4 raw = *(const uint4*)(src + u * 8);
    const unsigned short* s = (const unsigned short*)&raw;
    float4 o;
    int c = c0 + u * 8;
    o.x = fmaxf(fmaf(b2f(s[0]), nsc[c], nsh[c]), 0.f);
    o.y = fmaxf(fmaf(b2f(s[1]), nsc[c + 1], nsh[c + 1]), 0.f);
    o.z = fmaxf(fmaf(b2f(s[2]), nsc[c + 2], nsh[c + 2]), 0.f);
    o.w = fmaxf(fmaf(b2f(s[3]), nsc[c + 3], nsh[c + 3]), 0.f);
    *(float4*)(dst + u * 8) = o;
    o.x = fmaxf(fmaf(b2f(s[4]), nsc[c + 4], nsh[c + 4]), 0.f);
    o.y = fmaxf(fmaf(b2f(s[5]), nsc[c + 5], nsh[c + 5]), 0.f);
    o.z = fmaxf(fmaf(b2f(s[6]), nsc[c + 6], nsh[c + 6]), 0.f);
    o.w = fmaxf(fmaf(b2f(s[7]), nsc[c + 7], nsh[c + 7]), 0.f);
    *(float4*)(dst + u * 8 + 4) = o;
  }
}

extern "C" void kernel_launch(void* const* d_in, const int* in_sizes, int n_in,
                              void* d_out, int out_size, void* d_ws, size_t ws_size,
                              hipStream_t stream) {
  const float* x = (const float*)d_in[0];
  const float* adj = (const float*)d_in[2];
  const float* W1 = (const float*)d_in[3];
  const float* b1 = (const float*)d_in[4];
  const float* W2 = (const float*)d_in[5];
  const float* b2 = (const float*)d_in[6];
  const float* g_in = (const float*)d_in[7];
  const float* be_in = (const float*)d_in[8];
  const float* g_out = (const float*)d_in[9];
  const float* be_out = (const float*)d_in[10];
  float* out = (float*)d_out;

  char* ws = (char*)d_ws;
  unsigned short* hT = (unsigned short*)ws;                           // 8 MB
  unsigned short* z1b = (unsigned short*)(ws + 8ull * 1024 * 1024);   // 8 MB
  unsigned short* z2b = (unsigned short*)(ws + 16ull * 1024 * 1024);  // 8 MB
  unsigned short* W1T = (unsigned short*)(ws + 24ull * 1024 * 1024);  // 64 KB
  unsigned short* W2T = W1T + 2 * 128 * 128;                          // 64 KB
  float* stats = (float*)(ws + 25ull * 1024 * 1024);                  // 4 x 256 f32
  unsigned short* adjB = (unsigned short*)(ws + 26ull * 1024 * 1024); // 64 MB

  k0_prep<<<512 + 16384, 256, 0, stream>>>(x, adj, W1, W2, hT, W1T, W2T, adjB,
                                           stats);

  for (int l = 0; l < 2; l++) {
    float* st_in = stats + (l * 2 + 0) * 256;
    float* st_out = stats + (l * 2 + 1) * 256;
    kA_pool_lin<<<256, 256, 0, stream>>>(adjB, hT, W1T + l * 16384,
                                         b1 + l * 128, z1b, st_in,
                                         st_in + 128);
    kB_lin<<<512, 256, 0, stream>>>(z1b, st_in, st_in + 128, g_in + l * 128,
                                    be_in + l * 128, W2T + l * 16384,
                                    b2 + l * 128, z2b, st_out, st_out + 128);
    if (l == 0)
      k4_bnt<<<dim3(32, 8), 256, 0, stream>>>(z2b, st_out, st_out + 128, g_out,
                                              be_out, hT);
    else
      k4_out<<<256, 256, 0, stream>>>(z2b, st_out, st_out + 128, g_out + 128,
                                      be_out + 128, out);
  }
}